// Round 8
// baseline (71.620 us; speedup 1.0000x reference)
//
#include <hip/hip_runtime.h>
#include <hip/hip_bf16.h>

#define NDIGIT 10
#define DIM_IN 256
#define DIM_OUT 784
#define BATCH 16384
#define NCT 49                            // 784/16 col-tiles
#define MAX_P32 (BATCH / 32 + NDIGIT)     // 522 worst-case 32-row ptiles
#define G8_BLOCKS MAX_P32                 // one block per ptile

// ws layout:
//  ints [0..10]    bucket row offsets[11]
//  ints [40..50]   32-row ptile offsets[11] (padded, per expert)
//  ints [52]       total ptiles
//  ints [64 + j*16 + g]  per-hist-block partial counts (j<32, g<10)
//  ints [1024..17407]    idx[16384]
//  byte 69632..           W bf16 FRAG-PACKED: [g][ct:49][ks:8][lane:64][8]
//  byte 4,083,712..       A bf16 FRAG-PACKED: [p:522][fs:16][lane:64][8]
//                         fs = ks*2 + m  (m = 16-row half of the 32-row tile)
#define WS_IDX 1024
#define WS_WBF_BYTES 69632
#define WS_TF_BYTES (WS_WBF_BYTES + 2007040 * 2)   // 4,083,712

typedef __attribute__((ext_vector_type(4))) float f32x4;
typedef __attribute__((ext_vector_type(8))) short bf16x8;

__device__ __forceinline__ short f2bf(float f) {
    union { float f; unsigned u; } c; c.f = f;
    unsigned u = c.u;
    u += 0x7fffu + ((u >> 16) & 1u);   // RNE
    return (short)(u >> 16);
}

// blocks [0,980): pack megaW f32 -> bf16 in MFMA-fragment order (as round 7)
// blocks [980,1012): per-512-row label histograms
__global__ void prep_k(const float* __restrict__ megaW,
                       const int* __restrict__ label,
                       int* __restrict__ wsi,
                       short* __restrict__ wbf) {
    int b = blockIdx.x, t = threadIdx.x;
    if (b < 980) {
        int idx = b * 256 + t;            // 0..250879 = 490*8*64
        int gi = idx >> 9;                // g*49 + ct
        int ks = (idx >> 6) & 7;
        int l  = idx & 63;
        int g  = gi / 49;
        int ct = gi - g * 49;
        int col = ct * 16 + (l & 15);
        int k   = ks * 32 + ((l >> 4) << 3);
        const float* src = megaW + ((size_t)(g * DIM_OUT + col) * DIM_IN + k);
        f32x4 v0 = *(const f32x4*)src;
        f32x4 v1 = *(const f32x4*)(src + 4);
        bf16x8 o;
        o[0] = f2bf(v0[0]); o[1] = f2bf(v0[1]); o[2] = f2bf(v0[2]); o[3] = f2bf(v0[3]);
        o[4] = f2bf(v1[0]); o[5] = f2bf(v1[1]); o[6] = f2bf(v1[2]); o[7] = f2bf(v1[3]);
        *(bf16x8*)(wbf + (size_t)idx * 8) = o;
    } else {
        __shared__ int h[NDIGIT];
        int j = b - 980;
        if (t < NDIGIT) h[t] = 0;
        __syncthreads();
        int i0 = j * 512;
        atomicAdd(&h[label[i0 + t]], 1);
        atomicAdd(&h[label[i0 + 256 + t]], 1);
        __syncthreads();
        if (t < NDIGIT) wsi[64 + j * 16 + t] = h[t];
    }
}

// 32 blocks x 512 threads; block j owns rows [j*512, j*512+512)
__global__ void scatter2_k(const int* __restrict__ label, int* __restrict__ wsi) {
    __shared__ int tot[NDIGIT], bef[NDIGIT], base[NDIGIT + 1], cur[NDIGIT];
    int j = blockIdx.x, t = threadIdx.x;
    if (t < NDIGIT) {
        int s = 0, sb = 0;
        for (int jj = 0; jj < 32; ++jj) {
            int v = wsi[64 + jj * 16 + t];
            s += v;
            if (jj < j) sb += v;
        }
        tot[t] = s; bef[t] = sb;
    }
    __syncthreads();
    if (t == 0) {
        int off = 0;
        for (int g = 0; g < NDIGIT; ++g) { base[g] = off; off += tot[g]; }
        base[NDIGIT] = off;
    }
    __syncthreads();
    if (t < NDIGIT) cur[t] = base[t] + bef[t];
    __syncthreads();
    int i = j * 512 + t;
    int g = label[i];
    int r = atomicAdd(&cur[g], 1);
    wsi[WS_IDX + r] = i;
    if (j == 0 && t == 0) {
        int off = 0, p32 = 0;
        for (int g2 = 0; g2 < NDIGIT; ++g2) {
            wsi[g2] = off;
            wsi[40 + g2] = p32;
            off += tot[g2];
            p32 += (tot[g2] + 31) / 32;
        }
        wsi[10] = off;
        wsi[50] = p32;
        wsi[52] = p32;
    }
}

// gather theta rows into A-frag-packed bf16 tiles (one wave per ptile)
__global__ void gfrag_k(const float* __restrict__ theta,
                        const int* __restrict__ wsi,
                        short* __restrict__ thfrag) {
    int p = blockIdx.x * 4 + (threadIdx.x >> 6);
    int total = wsi[52];
    if (p >= total) return;
    int l = threadIdx.x & 63;
    int coff = (l < 11) ? wsi[40 + l] : 0x7fffffff;
    int boff = (l < 11) ? wsi[l] : 0;
    unsigned long long m = __ballot(p >= coff);
    int g = __popcll(m) - 1;
    int lc    = p - __shfl(coff, g);
    int start = __shfl(boff, g);
    int cnt   = __shfl(boff, g + 1) - start;
    int r16 = l & 15, hi = l >> 4;
    int rl0 = lc * 32 + r16;      if (rl0 > cnt - 1) rl0 = cnt - 1;
    int rl1 = lc * 32 + 16 + r16; if (rl1 > cnt - 1) rl1 = cnt - 1;
    int i0 = wsi[WS_IDX + start + rl0];
    int i1 = wsi[WS_IDX + start + rl1];
    short* dst = thfrag + (size_t)p * 8192 + l * 8;
    const float* s0b = theta + (size_t)i0 * DIM_IN + hi * 8;
    const float* s1b = theta + (size_t)i1 * DIM_IN + hi * 8;
#pragma unroll
    for (int ks = 0; ks < 8; ++ks) {
        f32x4 u0 = *(const f32x4*)(s0b + ks * 32);
        f32x4 u1 = *(const f32x4*)(s0b + ks * 32 + 4);
        f32x4 v0 = *(const f32x4*)(s1b + ks * 32);
        f32x4 v1 = *(const f32x4*)(s1b + ks * 32 + 4);
        bf16x8 o0, o1;
        o0[0] = f2bf(u0[0]); o0[1] = f2bf(u0[1]); o0[2] = f2bf(u0[2]); o0[3] = f2bf(u0[3]);
        o0[4] = f2bf(u1[0]); o0[5] = f2bf(u1[1]); o0[6] = f2bf(u1[2]); o0[7] = f2bf(u1[3]);
        o1[0] = f2bf(v0[0]); o1[1] = f2bf(v0[1]); o1[2] = f2bf(v0[2]); o1[3] = f2bf(v0[3]);
        o1[4] = f2bf(v1[0]); o1[5] = f2bf(v1[1]); o1[6] = f2bf(v1[2]); o1[7] = f2bf(v1[3]);
        *(bf16x8*)(dst + (ks * 2 + 0) * 512) = o0;
        *(bf16x8*)(dst + (ks * 2 + 1) * 512) = o1;
    }
}

// gemm8: one block per 32-row ptile; 4 waves split 49 col-tiles (stride 4).
// A frag-packed in 64 VGPR; B frag-packed streamed with 2-buffer prefetch.
// No LDS, no barriers, no conversions, no spill (bounds 256,2 -> 256 VGPR).

#define LOADB(B, CT) do {                                                      \
    const short* Bt_ = Wg + (size_t)(CT) * 4096 + l * 8;                       \
    _Pragma("unroll")                                                          \
    for (int ks = 0; ks < 8; ++ks)                                             \
        (B)[ks] = *(const bf16x8*)(Bt_ + ks * 512);                            \
} while (0)

#define TILE(B, CT) do {                                                       \
    float bias_ = bgb[(CT) * 16 + r16];                                        \
    f32x4 acc0_ = {0.f, 0.f, 0.f, 0.f}, acc1_ = {0.f, 0.f, 0.f, 0.f};         \
    _Pragma("unroll")                                                          \
    for (int ks = 0; ks < 8; ++ks) {                                           \
        acc0_ = __builtin_amdgcn_mfma_f32_16x16x32_bf16(a0[ks], (B)[ks], acc0_, 0, 0, 0); \
        acc1_ = __builtin_amdgcn_mfma_f32_16x16x32_bf16(a1[ks], (B)[ks], acc1_, 0, 0, 0); \
    }                                                                          \
    int colb_ = (CT) * 16 + r16;                                               \
    _Pragma("unroll")                                                          \
    for (int j = 0; j < 4; ++j) {                                              \
        if (or0[j] >= 0) {                                                     \
            float x_ = acc0_[j] + bias_;                                       \
            out[(size_t)or0[j] * DIM_OUT + colb_] = 1.0f / (1.0f + __expf(-x_)); \
        }                                                                      \
        if (or1[j] >= 0) {                                                     \
            float x_ = acc1_[j] + bias_;                                       \
            out[(size_t)or1[j] * DIM_OUT + colb_] = 1.0f / (1.0f + __expf(-x_)); \
        }                                                                      \
    }                                                                          \
} while (0)

__launch_bounds__(256, 2)
__global__ void moe_gemm8_k(const short* __restrict__ thfrag,
                            const float* __restrict__ megab,
                            const int* __restrict__ wsi,
                            const short* __restrict__ wbf,
                            float* __restrict__ out) {
    int Bid = blockIdx.x;
    const int q8 = G8_BLOCKS / 8, r8 = G8_BLOCKS % 8;   // 65, 2
    int xcd = Bid & 7, slot = Bid >> 3;
    int p = (xcd < r8 ? xcd * (q8 + 1) : r8 * (q8 + 1) + (xcd - r8) * q8) + slot;

    int total = wsi[52];
    if (p >= total) return;

    int tid = threadIdx.x;
    int wv = tid >> 6, l = tid & 63, r16 = l & 15, kg = l >> 4;

    // expert mapping via one ballot
    int coff = (l < 11) ? wsi[40 + l] : 0x7fffffff;
    int boff = (l < 11) ? wsi[l] : 0;
    unsigned long long mm = __ballot(p >= coff);
    int g = __popcll(mm) - 1;
    int lc    = p - __shfl(coff, g);
    int start = __shfl(boff, g);
    int cnt   = __shfl(boff, g + 1) - start;
    int rloc0 = lc * 32;
    int rc    = cnt - rloc0; if (rc > 32) rc = 32;

    // ---- A hoist: 16 coalesced 1 KB loads -> 64 VGPR, reused for all cts
    const short* Af = thfrag + (size_t)p * 8192 + l * 8;
    bf16x8 a0[8], a1[8];
#pragma unroll
    for (int ks = 0; ks < 8; ++ks) {
        a0[ks] = *(const bf16x8*)(Af + (ks * 2 + 0) * 512);
        a1[ks] = *(const bf16x8*)(Af + (ks * 2 + 1) * 512);
    }

    // output rows (C layout: col = l&15, row = kg*4 + j per 16-row half)
    const int* idxl = wsi + WS_IDX + start + rloc0;
    int or0[4], or1[4];
#pragma unroll
    for (int j = 0; j < 4; ++j) {
        int rl = kg * 4 + j;
        or0[j] = (rl < rc) ? idxl[rl] : -1;
        int rl1 = 16 + kg * 4 + j;
        or1[j] = (rl1 < rc) ? idxl[rl1] : -1;
    }

    const short* Wg  = wbf + (size_t)g * (NCT * 4096);
    const float* bgb = megab + (size_t)g * DIM_OUT;

    // ---- col-tile loop with explicit 2-buffer B prefetch (static names)
    bf16x8 bA[8], bB[8];
    int ct = wv;
    LOADB(bA, ct);
    while (true) {
        int c1 = ct + 4;
        if (c1 < NCT) {
            LOADB(bB, c1);
            TILE(bA, ct);
        } else {
            TILE(bA, ct);
            break;
        }
        int c2 = c1 + 4;
        if (c2 < NCT) {
            LOADB(bA, c2);
            TILE(bB, c1);
        } else {
            TILE(bB, c1);
            break;
        }
        ct = c2;
    }
}

extern "C" void kernel_launch(void* const* d_in, const int* in_sizes, int n_in,
                              void* d_out, int out_size, void* d_ws, size_t ws_size,
                              hipStream_t stream) {
    const float* theta = (const float*)d_in[0];
    const int*   label = (const int*)d_in[1];
    const float* megaW = (const float*)d_in[2];
    const float* megab = (const float*)d_in[3];
    float* out = (float*)d_out;
    int* wsi = (int*)d_ws;
    short* wbf    = (short*)((char*)d_ws + WS_WBF_BYTES);
    short* thfrag = (short*)((char*)d_ws + WS_TF_BYTES);

    prep_k    <<<1012, 256, 0, stream>>>(megaW, label, wsi, wbf);
    scatter2_k<<<32, 512, 0, stream>>>(label, wsi);
    gfrag_k   <<<(MAX_P32 + 3) / 4, 256, 0, stream>>>(theta, wsi, thfrag);
    moe_gemm8_k<<<G8_BLOCKS, 256, 0, stream>>>(thfrag, megab, wsi, wbf, out);
}

// Round 9
// 52.634 us; speedup vs baseline: 1.3607x; 1.3607x over previous
//
#include <hip/hip_runtime.h>
#include <hip/hip_bf16.h>

#define NDIGIT 10
#define DIM_IN 256
#define DIM_OUT 784
#define BATCH 16384
#define BM 64                           // rows per block (4 waves x 16)
#define BN 112                          // cols per block (7 x 16)
#define NCB 7                           // 784 / 112
#define MAX_MT (BATCH / BM + NDIGIT)    // 266 worst-case 64-row tiles
#define G9_BLOCKS (MAX_MT * NCB)        // 1862
#define QB 14336                        // K-quarter LDS: 112 rows x 128 B

// ws layout:
//  ints [0..10]    bucket row offsets[11]
//  ints [24]       total 64-row tiles
//  ints [64 + j*16 + g]  per-hist-block partial counts (j<32, g<10)
//  ints [600..875] per-tile desc: startRow(14b) | rc(7b)<<14 | g<<21
//  ints [1024..17407]    idx[16384]
//  byte 69632..           W bf16 row-major (2,007,040 shorts)
//  byte 4,083,712..       thsort bf16 (16384 x 256, sorted by label)
#define WS_IDX 1024
#define WS_DESC 600
#define WS_WBF_BYTES 69632
#define WS_TH_BYTES (WS_WBF_BYTES + 2007040 * 2)   // 4,083,712

typedef __attribute__((ext_vector_type(4))) float f32x4;
typedef __attribute__((ext_vector_type(8))) short bf16x8;

__device__ __forceinline__ short f2bf(float f) {
    union { float f; unsigned u; } c; c.f = f;
    unsigned u = c.u;
    u += 0x7fffu + ((u >> 16) & 1u);   // RNE
    return (short)(u >> 16);
}

__device__ __forceinline__ void gload16(const void* gp, void* lp) {
    __builtin_amdgcn_global_load_lds(
        (const __attribute__((address_space(1))) void*)gp,
        (__attribute__((address_space(3))) void*)lp, 16, 0, 0);
}

// blocks [0,980): convert megaW f32 -> bf16 (row-major); [980,1012): histograms
__global__ void prep_k(const float* __restrict__ megaW,
                       const int* __restrict__ label,
                       int* __restrict__ wsi,
                       short* __restrict__ wbf) {
    int b = blockIdx.x, t = threadIdx.x;
    if (b < 980) {
        int base = b * 2048 + t * 8;       // 980*2048 = 2,007,040 exact
        f32x4 v0 = *(const f32x4*)(megaW + base);
        f32x4 v1 = *(const f32x4*)(megaW + base + 4);
        bf16x8 o;
        o[0] = f2bf(v0[0]); o[1] = f2bf(v0[1]); o[2] = f2bf(v0[2]); o[3] = f2bf(v0[3]);
        o[4] = f2bf(v1[0]); o[5] = f2bf(v1[1]); o[6] = f2bf(v1[2]); o[7] = f2bf(v1[3]);
        *(bf16x8*)(wbf + base) = o;
    } else {
        __shared__ int h[NDIGIT];
        int j = b - 980;
        if (t < NDIGIT) h[t] = 0;
        __syncthreads();
        int i0 = j * 512;
        atomicAdd(&h[label[i0 + t]], 1);
        atomicAdd(&h[label[i0 + 256 + t]], 1);
        __syncthreads();
        if (t < NDIGIT) wsi[64 + j * 16 + t] = h[t];
    }
}

// 32 blocks x 512 threads; block j owns rows [j*512, j*512+512).
// Also builds the per-tile descriptor table (block 0) and tile count.
__global__ void scatter2_k(const int* __restrict__ label, int* __restrict__ wsi) {
    __shared__ int tot[NDIGIT], bef[NDIGIT], base[NDIGIT + 1], cur[NDIGIT], toff[NDIGIT + 1];
    int j = blockIdx.x, t = threadIdx.x;
    if (t < NDIGIT) {
        int s = 0, sb = 0;
        for (int jj = 0; jj < 32; ++jj) {
            int v = wsi[64 + jj * 16 + t];
            s += v;
            if (jj < j) sb += v;
        }
        tot[t] = s; bef[t] = sb;
    }
    __syncthreads();
    if (t == 0) {
        int off = 0, tf = 0;
        for (int g = 0; g < NDIGIT; ++g) {
            base[g] = off; toff[g] = tf;
            off += tot[g]; tf += (tot[g] + BM - 1) / BM;
        }
        base[NDIGIT] = off; toff[NDIGIT] = tf;
    }
    __syncthreads();
    if (t < NDIGIT) cur[t] = base[t] + bef[t];
    // per-tile descriptors (idempotent across blocks; do in block 0 only)
    if (j == 0) {
        int ptotal = toff[NDIGIT];
        for (int p = t; p < ptotal; p += 512) {
            int g2 = 0;
            while (p >= toff[g2 + 1]) ++g2;
            int row0 = (p - toff[g2]) * BM;
            int rcv = tot[g2] - row0; if (rcv > BM) rcv = BM;
            wsi[WS_DESC + p] = (base[g2] + row0) | (rcv << 14) | (g2 << 21);
        }
        if (t == 0) wsi[24] = ptotal;
    }
    __syncthreads();
    int i = j * 512 + t;
    int g = label[i];
    int r = atomicAdd(&cur[g], 1);
    wsi[WS_IDX + r] = i;
    if (j == 0 && t < NDIGIT) wsi[t] = base[t];
    if (j == 0 && t == 0) wsi[10] = base[NDIGIT];
}

// gather theta rows into sorted order, converted to bf16
__global__ void gth_k(const float* __restrict__ theta,
                      const int* __restrict__ wsi,
                      short* __restrict__ thsort) {
    int gid = blockIdx.x * 256 + threadIdx.x;
    int r = gid >> 5;
    int c8 = (gid & 31) << 3;
    int src = wsi[WS_IDX + r];
    const float* p = theta + (size_t)src * DIM_IN + c8;
    f32x4 v0 = *(const f32x4*)p;
    f32x4 v1 = *(const f32x4*)(p + 4);
    bf16x8 o;
    o[0] = f2bf(v0[0]); o[1] = f2bf(v0[1]); o[2] = f2bf(v0[2]); o[3] = f2bf(v0[3]);
    o[4] = f2bf(v1[0]); o[5] = f2bf(v1[1]); o[6] = f2bf(v1[2]); o[7] = f2bf(v1[3]);
    *(bf16x8*)(thsort + (size_t)r * DIM_IN + c8) = o;
}

// stage K-quarter q of the 112-row W panel (row-major, 512 B rows) into
// linear LDS; source pre-swizzled so the swizzled ds_read is conflict-free.
__device__ __forceinline__ void stage_q(const char* Wcb, int q, char* Bq, int tid) {
#pragma unroll
    for (int it = 0; it < 4; ++it) {
        int chunk = it * 256 + tid;            // 0..1023 (896 real)
        if (chunk >= 896) chunk -= 128;        // dup tail, benign
        int lbyte = chunk << 4;
        int L = lbyte ^ ((((lbyte >> 7) & 7)) << 4);   // involution
        int row = L >> 7, koff = L & 127;
        gload16(Wcb + row * 512 + q * 128 + koff, Bq + lbyte);
    }
}

#define COMPUTE(Q) do {                                                        \
    _Pragma("unroll")                                                          \
    for (int ksl = 0; ksl < 2; ++ksl) {                                        \
        _Pragma("unroll")                                                      \
        for (int ns = 0; ns < NCB; ++ns) {                                     \
            int n_ = ns * 16 + r16;                                            \
            int byte_ = (n_ << 7) + (ksl << 6) + (kg << 4);                    \
            byte_ ^= (n_ & 7) << 4;                                            \
            bf16x8 bfr_ = *(const bf16x8*)(Bs + byte_);                        \
            acc[ns] = __builtin_amdgcn_mfma_f32_16x16x32_bf16(                 \
                a[(Q) * 2 + ksl], bfr_, acc[ns], 0, 0, 0);                     \
        }                                                                      \
    }                                                                          \
} while (0)

// gemm9: gemm4 geometry at max residency. 14.3 KB LDS single-buffer,
// VGPR<=64 (launch_bounds 256,8) -> 8 blocks/CU = 32 waves/CU.
__launch_bounds__(256, 8)
__global__ void moe_gemm9_k(const short* __restrict__ thsort,
                            const float* __restrict__ megab,
                            const int* __restrict__ wsi,
                            const short* __restrict__ wbf,
                            float* __restrict__ out) {
    __shared__ char Bs[QB];

    int Bid = blockIdx.x;
    const int q8 = G9_BLOCKS / 8, r8 = G9_BLOCKS % 8;   // 232, 6
    int xcd = Bid & 7, slot = Bid >> 3;
    int w = (xcd < r8 ? xcd * (q8 + 1) : r8 * (q8 + 1) + (xcd - r8) * q8) + slot;
    int mt = w / NCB, cb = w % NCB;

    int total = wsi[24];
    if (mt >= total) return;            // uniform exit before barriers

    int d = wsi[WS_DESC + mt];
    int startRow = d & 0x3FFF;
    int rc = (d >> 14) & 0x7F;
    int g  = d >> 21;

    int tid = threadIdx.x;
    int wv = tid >> 6, l = tid & 63, r16 = l & 15, kg = l >> 4;

    // ---- A fragments from sorted bf16 (no conversion)
    int mloc = wv * 16 + r16; if (mloc >= rc) mloc = rc - 1;
    const short* Ar = thsort + (size_t)(startRow + mloc) * DIM_IN + kg * 8;
    bf16x8 a[8];
#pragma unroll
    for (int ks = 0; ks < 8; ++ks)
        a[ks] = *(const bf16x8*)(Ar + ks * 32);

    const char* Wcb = (const char*)(wbf + ((size_t)g * DIM_OUT + (size_t)cb * BN) * DIM_IN);

    f32x4 acc[NCB];
#pragma unroll
    for (int ns = 0; ns < NCB; ++ns) acc[ns] = (f32x4){0.f, 0.f, 0.f, 0.f};

    // ---- 4 quarter phases: stage -> sync -> compute -> sync
#pragma unroll
    for (int q = 0; q < 4; ++q) {
        stage_q(Wcb, q, Bs, tid);
        __syncthreads();                // drains gload_lds; buffer ready
        COMPUTE(q);
        if (q < 3) __syncthreads();     // readers done before overwrite
    }

    // ---- epilogue: bias + sigmoid + cached scattered stores
    const float* bg = megab + (size_t)g * DIM_OUT + (size_t)cb * BN;
    const int* idxl = wsi + WS_IDX + startRow;
    int rbase = wv * 16 + kg * 4;
    int orow[4];
#pragma unroll
    for (int j = 0; j < 4; ++j)
        orow[j] = (rbase + j < rc) ? idxl[rbase + j] : -1;

#pragma unroll
    for (int ns = 0; ns < NCB; ++ns) {
        int nloc = ns * 16 + r16;
        float bias = bg[nloc];
#pragma unroll
        for (int j = 0; j < 4; ++j) {
            if (orow[j] >= 0) {
                float x = acc[ns][j] + bias;
                out[(size_t)orow[j] * DIM_OUT + cb * BN + nloc] = 1.0f / (1.0f + __expf(-x));
            }
        }
    }
}

extern "C" void kernel_launch(void* const* d_in, const int* in_sizes, int n_in,
                              void* d_out, int out_size, void* d_ws, size_t ws_size,
                              hipStream_t stream) {
    const float* theta = (const float*)d_in[0];
    const int*   label = (const int*)d_in[1];
    const float* megaW = (const float*)d_in[2];
    const float* megab = (const float*)d_in[3];
    float* out = (float*)d_out;
    int* wsi = (int*)d_ws;
    short* wbf    = (short*)((char*)d_ws + WS_WBF_BYTES);
    short* thsort = (short*)((char*)d_ws + WS_TH_BYTES);

    prep_k    <<<1012, 256, 0, stream>>>(megaW, label, wsi, wbf);
    scatter2_k<<<32, 512, 0, stream>>>(label, wsi);
    gth_k     <<<2048, 256, 0, stream>>>(theta, wsi, thsort);
    moe_gemm9_k<<<G9_BLOCKS, 256, 0, stream>>>(thsort, megab, wsi, wbf, out);
}

// Round 10
// 47.247 us; speedup vs baseline: 1.5159x; 1.1140x over previous
//
#include <hip/hip_runtime.h>
#include <hip/hip_bf16.h>

#define NDIGIT 10
#define DIM_IN 256
#define DIM_OUT 784
#define BATCH 16384
#define BM 64                           // rows per block (4 waves x 16)
#define BN 112                          // cols per block (7 x 16)
#define NCB 7                           // 784 / 112
#define MAX_MT (BATCH / BM + NDIGIT)    // 266 worst-case 64-row tiles
#define G_BLOCKS (MAX_MT * NCB)         // 1862
#define QB 14336                        // one K-quarter: 112 rows x 128 B

// ws layout:
//  ints [0..10]    bucket row offsets[11]
//  ints [12..22]   64-row tile offsets[11] (fallback)
//  ints [24]       total 64-row tiles
//  ints [64 + j*16 + g]  per-hist-block partial counts (j<32, g<10)
//  ints [600..875] per-tile desc: startRow | rc<<14 | g<<21
//  ints [1024..17407]    idx[16384]
//  byte 69632..           W bf16 row-major (2,007,040 shorts)
//  byte 4,083,712..       thsort bf16 (16384 x 256, sorted by label)
#define WS_IDX 1024
#define WS_DESC 600
#define WS_WBF_BYTES 69632
#define WS_TH_BYTES (WS_WBF_BYTES + 2007040 * 2)   // 4,083,712
#define WS_NEED (WS_TH_BYTES + BATCH * DIM_IN * 2) // 12,472,320

typedef __attribute__((ext_vector_type(4))) float f32x4;
typedef __attribute__((ext_vector_type(8))) short bf16x8;

__device__ __forceinline__ short f2bf(float f) {
    union { float f; unsigned u; } c; c.f = f;
    unsigned u = c.u;
    u += 0x7fffu + ((u >> 16) & 1u);   // RNE
    return (short)(u >> 16);
}

__device__ __forceinline__ void gload16(const void* gp, void* lp) {
    __builtin_amdgcn_global_load_lds(
        (const __attribute__((address_space(1))) void*)gp,
        (__attribute__((address_space(3))) void*)lp, 16, 0, 0);
}

// blocks [0,980): convert megaW f32 -> bf16 (row-major); [980,1012): histograms
__global__ void prep_k(const float* __restrict__ megaW,
                       const int* __restrict__ label,
                       int* __restrict__ wsi,
                       short* __restrict__ wbf) {
    int b = blockIdx.x, t = threadIdx.x;
    if (b < 980) {
        int base = b * 2048 + t * 8;
        f32x4 v0 = *(const f32x4*)(megaW + base);
        f32x4 v1 = *(const f32x4*)(megaW + base + 4);
        bf16x8 o;
        o[0] = f2bf(v0[0]); o[1] = f2bf(v0[1]); o[2] = f2bf(v0[2]); o[3] = f2bf(v0[3]);
        o[4] = f2bf(v1[0]); o[5] = f2bf(v1[1]); o[6] = f2bf(v1[2]); o[7] = f2bf(v1[3]);
        *(bf16x8*)(wbf + base) = o;
    } else {
        __shared__ int h[NDIGIT];
        int j = b - 980;
        if (t < NDIGIT) h[t] = 0;
        __syncthreads();
        int i0 = j * 512;
        atomicAdd(&h[label[i0 + t]], 1);
        atomicAdd(&h[label[i0 + 256 + t]], 1);
        __syncthreads();
        if (t < NDIGIT) wsi[64 + j * 16 + t] = h[t];
    }
}

// 32 blocks x 512 threads; block j owns rows [j*512, j*512+512).
// Block 0 also builds bucket offsets, tile offsets, and the desc table.
__global__ void scatter2_k(const int* __restrict__ label, int* __restrict__ wsi) {
    __shared__ int tot[NDIGIT], bef[NDIGIT], base[NDIGIT + 1], cur[NDIGIT], toff[NDIGIT + 1];
    int j = blockIdx.x, t = threadIdx.x;
    if (t < NDIGIT) {
        int s = 0, sb = 0;
        for (int jj = 0; jj < 32; ++jj) {
            int v = wsi[64 + jj * 16 + t];
            s += v;
            if (jj < j) sb += v;
        }
        tot[t] = s; bef[t] = sb;
    }
    __syncthreads();
    if (t == 0) {
        int off = 0, tf = 0;
        for (int g = 0; g < NDIGIT; ++g) {
            base[g] = off; toff[g] = tf;
            off += tot[g]; tf += (tot[g] + BM - 1) / BM;
        }
        base[NDIGIT] = off; toff[NDIGIT] = tf;
    }
    __syncthreads();
    if (t < NDIGIT) cur[t] = base[t] + bef[t];
    if (j == 0) {
        int ptotal = toff[NDIGIT];
        for (int p = t; p < ptotal; p += 512) {
            int g2 = 0;
            while (p >= toff[g2 + 1]) ++g2;
            int row0 = (p - toff[g2]) * BM;
            int rcv = tot[g2] - row0; if (rcv > BM) rcv = BM;
            wsi[WS_DESC + p] = (base[g2] + row0) | (rcv << 14) | (g2 << 21);
        }
        if (t < NDIGIT) { wsi[t] = base[t]; wsi[12 + t] = toff[t]; }
        if (t == 0) {
            wsi[10] = base[NDIGIT]; wsi[22] = toff[NDIGIT]; wsi[24] = toff[NDIGIT];
        }
    }
    __syncthreads();
    int i = j * 512 + t;
    int g = label[i];
    int r = atomicAdd(&cur[g], 1);
    wsi[WS_IDX + r] = i;
}

// gather theta rows into sorted order, converted to bf16
__global__ void gth_k(const float* __restrict__ theta,
                      const int* __restrict__ wsi,
                      short* __restrict__ thsort) {
    int gid = blockIdx.x * 256 + threadIdx.x;
    int r = gid >> 5;
    int c8 = (gid & 31) << 3;
    int src = wsi[WS_IDX + r];
    const float* p = theta + (size_t)src * DIM_IN + c8;
    f32x4 v0 = *(const f32x4*)p;
    f32x4 v1 = *(const f32x4*)(p + 4);
    bf16x8 o;
    o[0] = f2bf(v0[0]); o[1] = f2bf(v0[1]); o[2] = f2bf(v0[2]); o[3] = f2bf(v0[3]);
    o[4] = f2bf(v1[0]); o[5] = f2bf(v1[1]); o[6] = f2bf(v1[2]); o[7] = f2bf(v1[3]);
    *(bf16x8*)(thsort + (size_t)r * DIM_IN + c8) = o;
}

// stage K-quarter q (112 rows x 128 B) into linear LDS; source pre-swizzled
// (r9 layout: measured 0 bank conflicts).
__device__ __forceinline__ void stage_q(const char* Wcb, int q, char* Bq, int tid) {
#pragma unroll
    for (int it = 0; it < 4; ++it) {
        int chunk = it * 256 + tid;            // 0..1023 (896 real)
        if (chunk >= 896) chunk -= 128;        // dup tail, benign
        int lbyte = chunk << 4;
        int L = lbyte ^ ((((lbyte >> 7) & 7)) << 4);   // involution
        int row = L >> 7, koff = L & 127;
        gload16(Wcb + row * 512 + q * 128 + koff, Bq + lbyte);
    }
}

#define COMPUTE_Q(Q, BUF) do {                                                 \
    _Pragma("unroll")                                                          \
    for (int ksl = 0; ksl < 2; ++ksl) {                                        \
        _Pragma("unroll")                                                      \
        for (int ns = 0; ns < NCB; ++ns) {                                     \
            int n_ = ns * 16 + r16;                                            \
            int byte_ = (n_ << 7) + (ksl << 6) + (kg << 4);                    \
            byte_ ^= (n_ & 7) << 4;                                            \
            bf16x8 bfr_ = *(const bf16x8*)((const char*)(BUF) + byte_);        \
            acc[ns] = __builtin_amdgcn_mfma_f32_16x16x32_bf16(                 \
                a[(Q) * 2 + ksl], bfr_, acc[ns], 0, 0, 0);                     \
        }                                                                      \
    }                                                                          \
} while (0)

// gemm10: gemm4 geometry (proven clean writes @ ~2.4 blocks/CU), desc-table
// startup, bf16 pre-sorted A, r9 0-conflict LDS reads, 2 phases x 2 quarters.
__launch_bounds__(256, 4)
__global__ void moe_gemm10_k(const short* __restrict__ thsort,
                             const float* __restrict__ megab,
                             const int* __restrict__ wsi,
                             const short* __restrict__ wbf,
                             float* __restrict__ out) {
    __shared__ char Bs[2 * QB];         // 28672 B

    int Bid = blockIdx.x;
    const int q8 = G_BLOCKS / 8, r8 = G_BLOCKS % 8;   // 232, 6
    int xcd = Bid & 7, slot = Bid >> 3;
    int w = (xcd < r8 ? xcd * (q8 + 1) : r8 * (q8 + 1) + (xcd - r8) * q8) + slot;
    int mt = w / NCB, cb = w % NCB;

    int total = wsi[24];
    if (mt >= total) return;            // uniform exit before barriers

    int d = wsi[WS_DESC + mt];
    int startRow = d & 0x3FFF;
    int rc = (d >> 14) & 0x7F;
    int g  = d >> 21;

    int tid = threadIdx.x;
    int wv = tid >> 6, l = tid & 63, r16 = l & 15, kg = l >> 4;

    const char* Wcb = (const char*)(wbf + ((size_t)g * DIM_OUT + (size_t)cb * BN) * DIM_IN);

    // ---- stage quarters 0,1 (async, overlaps A-loads below)
    stage_q(Wcb, 0, Bs, tid);
    stage_q(Wcb, 1, Bs + QB, tid);

    // ---- A fragments from sorted bf16 (no conversion)
    int mloc = wv * 16 + r16; if (mloc >= rc) mloc = rc - 1;
    const short* Ar = thsort + (size_t)(startRow + mloc) * DIM_IN + kg * 8;
    bf16x8 a[8];
#pragma unroll
    for (int ks = 0; ks < 8; ++ks)
        a[ks] = *(const bf16x8*)(Ar + ks * 32);

    f32x4 acc[NCB];
#pragma unroll
    for (int ns = 0; ns < NCB; ++ns) acc[ns] = (f32x4){0.f, 0.f, 0.f, 0.f};

    __syncthreads();                    // phase-0 staged (drains vmcnt)
    COMPUTE_Q(0, Bs);
    COMPUTE_Q(1, Bs + QB);
    __syncthreads();                    // readers done before overwrite

    stage_q(Wcb, 2, Bs, tid);
    stage_q(Wcb, 3, Bs + QB, tid);
    __syncthreads();                    // phase-1 staged
    COMPUTE_Q(2, Bs);
    COMPUTE_Q(3, Bs + QB);

    // ---- epilogue: bias + sigmoid + cached scattered stores (gemm4-exact)
    const float* bg = megab + (size_t)g * DIM_OUT + (size_t)cb * BN;
    const int* idxl = wsi + WS_IDX + startRow;
    int rbase = wv * 16 + kg * 4;
    int orow[4];
#pragma unroll
    for (int j = 0; j < 4; ++j)
        orow[j] = (rbase + j < rc) ? idxl[rbase + j] : -1;

#pragma unroll
    for (int ns = 0; ns < NCB; ++ns) {
        int nloc = ns * 16 + r16;
        float bias = bg[nloc];
#pragma unroll
        for (int j = 0; j < 4; ++j) {
            if (orow[j] >= 0) {
                float x = acc[ns][j] + bias;
                out[(size_t)orow[j] * DIM_OUT + cb * BN + nloc] = 1.0f / (1.0f + __expf(-x));
            }
        }
    }
}

// =============== fallback (round-4 path; needs only wbf) ===============
__launch_bounds__(256, 4)
__global__ void moe_gemm4_k(const float* __restrict__ theta,
                            const float* __restrict__ megab,
                            const int* __restrict__ wsi,
                            const short* __restrict__ wbf,
                            float* __restrict__ out) {
    __shared__ short Bsf[BN * 128];
    int Bid = blockIdx.x;
    const int q8 = G_BLOCKS / 8, r8 = G_BLOCKS % 8;
    int xcd = Bid & 7, slot = Bid >> 3;
    int w = (xcd < r8 ? xcd * (q8 + 1) : r8 * (q8 + 1) + (xcd - r8) * q8) + slot;
    int mt = w / NCB, cb = w % NCB;
    int total = wsi[24];
    if (mt >= total) return;
    int g = 0;
    while (mt >= wsi[12 + g + 1]) ++g;
    int lt    = mt - wsi[12 + g];
    int start = wsi[g];
    int cnt   = wsi[g + 1] - start;
    int row0  = lt * BM;
    int rc    = min(BM, cnt - row0);
    int tid = threadIdx.x;
    int wv = tid >> 6, l = tid & 63, r16 = l & 15, kg = l >> 4;
    const char* Wcb = (const char*)(wbf + ((size_t)g * DIM_OUT + (size_t)cb * BN) * DIM_IN);
#pragma unroll
    for (int it = 0; it < 7; ++it) {
        int lbyte = (it * 256 + tid) << 4;
        int L = lbyte ^ (((lbyte >> 8) & 7) << 4);
        int srcoff = ((L >> 8) << 9) + (L & 255);
        gload16(Wcb + srcoff, (char*)Bsf + lbyte);
    }
    const int* idxlist = wsi + WS_IDX + start + row0;
    int mloc = wv * 16 + r16;
    int asrc = (mloc < rc) ? idxlist[mloc] : idxlist[0];
    const float* Arow = theta + (size_t)asrc * DIM_IN;
    bf16x8 a[8];
#pragma unroll
    for (int ks = 0; ks < 8; ++ks) {
        int k0 = ks * 32 + kg * 8;
        f32x4 v0 = *(const f32x4*)(Arow + k0);
        f32x4 v1 = *(const f32x4*)(Arow + k0 + 4);
        bf16x8 af;
        af[0] = f2bf(v0[0]); af[1] = f2bf(v0[1]);
        af[2] = f2bf(v0[2]); af[3] = f2bf(v0[3]);
        af[4] = f2bf(v1[0]); af[5] = f2bf(v1[1]);
        af[6] = f2bf(v1[2]); af[7] = f2bf(v1[3]);
        a[ks] = af;
    }
    f32x4 acc[NCB];
#pragma unroll
    for (int ns = 0; ns < NCB; ++ns) acc[ns] = (f32x4){0.f, 0.f, 0.f, 0.f};
    __syncthreads();
#pragma unroll
    for (int ks = 0; ks < 4; ++ks)
#pragma unroll
        for (int ns = 0; ns < NCB; ++ns) {
            int n = ns * 16 + r16;
            int byte = (n << 8) + (ks << 6) + (kg << 4);
            byte ^= (n & 7) << 4;
            bf16x8 b = *(const bf16x8*)((const char*)Bsf + byte);
            acc[ns] = __builtin_amdgcn_mfma_f32_16x16x32_bf16(a[ks], b, acc[ns], 0, 0, 0);
        }
    __syncthreads();
#pragma unroll
    for (int it = 0; it < 7; ++it) {
        int lbyte = (it * 256 + tid) << 4;
        int L = lbyte ^ (((lbyte >> 8) & 7) << 4);
        int srcoff = ((L >> 8) << 9) + (L & 255) + 256;
        gload16(Wcb + srcoff, (char*)Bsf + lbyte);
    }
    __syncthreads();
#pragma unroll
    for (int ks = 0; ks < 4; ++ks)
#pragma unroll
        for (int ns = 0; ns < NCB; ++ns) {
            int n = ns * 16 + r16;
            int byte = (n << 8) + (ks << 6) + (kg << 4);
            byte ^= (n & 7) << 4;
            bf16x8 b = *(const bf16x8*)((const char*)Bsf + byte);
            acc[ns] = __builtin_amdgcn_mfma_f32_16x16x32_bf16(a[4 + ks], b, acc[ns], 0, 0, 0);
        }
    const float* bg = megab + (size_t)g * DIM_OUT + (size_t)cb * BN;
    int rbase = wv * 16 + kg * 4;
    int orow[4];
#pragma unroll
    for (int j = 0; j < 4; ++j)
        orow[j] = (rbase + j < rc) ? idxlist[rbase + j] : -1;
#pragma unroll
    for (int ns = 0; ns < NCB; ++ns) {
        int nloc = ns * 16 + r16;
        float bias = bg[nloc];
#pragma unroll
        for (int j = 0; j < 4; ++j) {
            if (orow[j] >= 0) {
                float x = acc[ns][j] + bias;
                out[(size_t)orow[j] * DIM_OUT + cb * BN + nloc] = 1.0f / (1.0f + __expf(-x));
            }
        }
    }
}

extern "C" void kernel_launch(void* const* d_in, const int* in_sizes, int n_in,
                              void* d_out, int out_size, void* d_ws, size_t ws_size,
                              hipStream_t stream) {
    const float* theta = (const float*)d_in[0];
    const int*   label = (const int*)d_in[1];
    const float* megaW = (const float*)d_in[2];
    const float* megab = (const float*)d_in[3];
    float* out = (float*)d_out;
    int* wsi = (int*)d_ws;
    short* wbf = (short*)((char*)d_ws + WS_WBF_BYTES);

    prep_k    <<<1012, 256, 0, stream>>>(megaW, label, wsi, wbf);
    scatter2_k<<<32, 512, 0, stream>>>(label, wsi);

    if (ws_size >= (size_t)WS_NEED) {
        short* thsort = (short*)((char*)d_ws + WS_TH_BYTES);
        gth_k      <<<2048, 256, 0, stream>>>(theta, wsi, thsort);
        moe_gemm10_k<<<G_BLOCKS, 256, 0, stream>>>(thsort, megab, wsi, wbf, out);
    } else {
        moe_gemm4_k<<<G_BLOCKS, 256, 0, stream>>>(theta, megab, wsi, wbf, out);
    }
}

// Round 11
// 43.312 us; speedup vs baseline: 1.6536x; 1.0908x over previous
//
#include <hip/hip_runtime.h>
#include <hip/hip_bf16.h>

#define NDIGIT 10
#define DIM_IN 256
#define DIM_OUT 784
#define BATCH 16384
#define BM 64                           // rows per block (4 waves x 16)
#define BN 112                          // cols per block (7 x 16)
#define NCB 7                           // 784 / 112
#define MAX_MT (BATCH / BM + NDIGIT)    // 266 worst-case 64-row tiles
#define G_BLOCKS (MAX_MT * NCB)         // 1862
#define QB 14336                        // one K-quarter: 112 rows x 128 B
#define RBSTRIDE 116                    // rowbuf row stride (dwords): 4*116%32=16 -> 2-way max
#define LDS_BYTES 29696                 // max(2*QB, 4 waves*16*116*4 = 29696)

// ws layout:
//  ints [0..10]    bucket row offsets[11]
//  ints [12..22]   64-row tile offsets[11] (fallback)
//  ints [24]       total 64-row tiles
//  ints [64 + j*16 + g]  per-hist-block partial counts (j<32, g<10)
//  ints [600..875] per-tile desc: startRow | rc<<14 | g<<21
//  ints [1024..17407]    idx[16384]
//  byte 69632..           W bf16 row-major (2,007,040 shorts)
//  byte 4,083,712..       thsort bf16 (16384 x 256, sorted by label)
#define WS_IDX 1024
#define WS_DESC 600
#define WS_WBF_BYTES 69632
#define WS_TH_BYTES (WS_WBF_BYTES + 2007040 * 2)   // 4,083,712
#define WS_NEED (WS_TH_BYTES + BATCH * DIM_IN * 2) // 12,472,320

typedef __attribute__((ext_vector_type(4))) float f32x4;
typedef __attribute__((ext_vector_type(8))) short bf16x8;

__device__ __forceinline__ short f2bf(float f) {
    union { float f; unsigned u; } c; c.f = f;
    unsigned u = c.u;
    u += 0x7fffu + ((u >> 16) & 1u);   // RNE
    return (short)(u >> 16);
}

__device__ __forceinline__ void gload16(const void* gp, void* lp) {
    __builtin_amdgcn_global_load_lds(
        (const __attribute__((address_space(1))) void*)gp,
        (__attribute__((address_space(3))) void*)lp, 16, 0, 0);
}

// blocks [0,980): convert megaW f32 -> bf16 (row-major); [980,1012): histograms
__global__ void prep_k(const float* __restrict__ megaW,
                       const int* __restrict__ label,
                       int* __restrict__ wsi,
                       short* __restrict__ wbf) {
    int b = blockIdx.x, t = threadIdx.x;
    if (b < 980) {
        int base = b * 2048 + t * 8;
        f32x4 v0 = *(const f32x4*)(megaW + base);
        f32x4 v1 = *(const f32x4*)(megaW + base + 4);
        bf16x8 o;
        o[0] = f2bf(v0[0]); o[1] = f2bf(v0[1]); o[2] = f2bf(v0[2]); o[3] = f2bf(v0[3]);
        o[4] = f2bf(v1[0]); o[5] = f2bf(v1[1]); o[6] = f2bf(v1[2]); o[7] = f2bf(v1[3]);
        *(bf16x8*)(wbf + base) = o;
    } else {
        __shared__ int h[NDIGIT];
        int j = b - 980;
        if (t < NDIGIT) h[t] = 0;
        __syncthreads();
        int i0 = j * 512;
        atomicAdd(&h[label[i0 + t]], 1);
        atomicAdd(&h[label[i0 + 256 + t]], 1);
        __syncthreads();
        if (t < NDIGIT) wsi[64 + j * 16 + t] = h[t];
    }
}

// 32 blocks x 512 threads; block j owns rows [j*512, j*512+512).
// Block 0 also builds bucket offsets, tile offsets, and the desc table.
__global__ void scatter2_k(const int* __restrict__ label, int* __restrict__ wsi) {
    __shared__ int tot[NDIGIT], bef[NDIGIT], base[NDIGIT + 1], cur[NDIGIT], toff[NDIGIT + 1];
    int j = blockIdx.x, t = threadIdx.x;
    if (t < NDIGIT) {
        int s = 0, sb = 0;
        for (int jj = 0; jj < 32; ++jj) {
            int v = wsi[64 + jj * 16 + t];
            s += v;
            if (jj < j) sb += v;
        }
        tot[t] = s; bef[t] = sb;
    }
    __syncthreads();
    if (t == 0) {
        int off = 0, tf = 0;
        for (int g = 0; g < NDIGIT; ++g) {
            base[g] = off; toff[g] = tf;
            off += tot[g]; tf += (tot[g] + BM - 1) / BM;
        }
        base[NDIGIT] = off; toff[NDIGIT] = tf;
    }
    __syncthreads();
    if (t < NDIGIT) cur[t] = base[t] + bef[t];
    if (j == 0) {
        int ptotal = toff[NDIGIT];
        for (int p = t; p < ptotal; p += 512) {
            int g2 = 0;
            while (p >= toff[g2 + 1]) ++g2;
            int row0 = (p - toff[g2]) * BM;
            int rcv = tot[g2] - row0; if (rcv > BM) rcv = BM;
            wsi[WS_DESC + p] = (base[g2] + row0) | (rcv << 14) | (g2 << 21);
        }
        if (t < NDIGIT) { wsi[t] = base[t]; wsi[12 + t] = toff[t]; }
        if (t == 0) {
            wsi[10] = base[NDIGIT]; wsi[22] = toff[NDIGIT]; wsi[24] = toff[NDIGIT];
        }
    }
    __syncthreads();
    int i = j * 512 + t;
    int g = label[i];
    int r = atomicAdd(&cur[g], 1);
    wsi[WS_IDX + r] = i;
}

// gather theta rows into sorted order, converted to bf16
__global__ void gth_k(const float* __restrict__ theta,
                      const int* __restrict__ wsi,
                      short* __restrict__ thsort) {
    int gid = blockIdx.x * 256 + threadIdx.x;
    int r = gid >> 5;
    int c8 = (gid & 31) << 3;
    int src = wsi[WS_IDX + r];
    const float* p = theta + (size_t)src * DIM_IN + c8;
    f32x4 v0 = *(const f32x4*)p;
    f32x4 v1 = *(const f32x4*)(p + 4);
    bf16x8 o;
    o[0] = f2bf(v0[0]); o[1] = f2bf(v0[1]); o[2] = f2bf(v0[2]); o[3] = f2bf(v0[3]);
    o[4] = f2bf(v1[0]); o[5] = f2bf(v1[1]); o[6] = f2bf(v1[2]); o[7] = f2bf(v1[3]);
    *(bf16x8*)(thsort + (size_t)r * DIM_IN + c8) = o;
}

// stage K-quarter q (112 rows x 128 B) into linear LDS; source pre-swizzled
// (r9 layout: measured 0 bank conflicts).
__device__ __forceinline__ void stage_q(const char* Wcb, int q, char* Bq, int tid) {
#pragma unroll
    for (int it = 0; it < 4; ++it) {
        int chunk = it * 256 + tid;            // 0..1023 (896 real)
        if (chunk >= 896) chunk -= 128;        // dup tail, benign
        int lbyte = chunk << 4;
        int L = lbyte ^ ((((lbyte >> 7) & 7)) << 4);   // involution
        int row = L >> 7, koff = L & 127;
        gload16(Wcb + row * 512 + q * 128 + koff, Bq + lbyte);
    }
}

#define COMPUTE_Q(Q, BUF) do {                                                 \
    _Pragma("unroll")                                                          \
    for (int ksl = 0; ksl < 2; ++ksl) {                                        \
        _Pragma("unroll")                                                      \
        for (int ns = 0; ns < NCB; ++ns) {                                     \
            int n_ = ns * 16 + r16;                                            \
            int byte_ = (n_ << 7) + (ksl << 6) + (kg << 4);                    \
            byte_ ^= (n_ & 7) << 4;                                            \
            bf16x8 bfr_ = *(const bf16x8*)((const char*)(BUF) + byte_);        \
            acc[ns] = __builtin_amdgcn_mfma_f32_16x16x32_bf16(                 \
                a[(Q) * 2 + ksl], bfr_, acc[ns], 0, 0, 0);                     \
        }                                                                      \
    }                                                                          \
} while (0)

// gemm11: identical to gemm10 through the MFMA phases; epilogue replaced by an
// LDS row-transpose so stores become 448-B-contiguous coalesced runs instead of
// scattered 64-B half-line segments. Clean A/B on the store path.
__launch_bounds__(256, 4)
__global__ void moe_gemm11_k(const short* __restrict__ thsort,
                             const float* __restrict__ megab,
                             const int* __restrict__ wsi,
                             const short* __restrict__ wbf,
                             float* __restrict__ out) {
    __shared__ char Bs[LDS_BYTES];      // B-stage (28672 B) then rowbuf (29696 B)

    int Bid = blockIdx.x;
    const int q8 = G_BLOCKS / 8, r8 = G_BLOCKS % 8;   // 232, 6
    int xcd = Bid & 7, slot = Bid >> 3;
    int w = (xcd < r8 ? xcd * (q8 + 1) : r8 * (q8 + 1) + (xcd - r8) * q8) + slot;
    int mt = w / NCB, cb = w % NCB;

    int total = wsi[24];
    if (mt >= total) return;            // uniform exit before barriers

    int d = wsi[WS_DESC + mt];
    int startRow = d & 0x3FFF;
    int rc = (d >> 14) & 0x7F;
    int g  = d >> 21;

    int tid = threadIdx.x;
    int wv = tid >> 6, l = tid & 63, r16 = l & 15, kg = l >> 4;

    const char* Wcb = (const char*)(wbf + ((size_t)g * DIM_OUT + (size_t)cb * BN) * DIM_IN);

    // ---- stage quarters 0,1 (async, overlaps A-loads below)
    stage_q(Wcb, 0, Bs, tid);
    stage_q(Wcb, 1, Bs + QB, tid);

    // ---- A fragments from sorted bf16 (no conversion)
    int mloc = wv * 16 + r16; if (mloc >= rc) mloc = rc - 1;
    const short* Ar = thsort + (size_t)(startRow + mloc) * DIM_IN + kg * 8;
    bf16x8 a[8];
#pragma unroll
    for (int ks = 0; ks < 8; ++ks)
        a[ks] = *(const bf16x8*)(Ar + ks * 32);

    f32x4 acc[NCB];
#pragma unroll
    for (int ns = 0; ns < NCB; ++ns) acc[ns] = (f32x4){0.f, 0.f, 0.f, 0.f};

    __syncthreads();                    // phase-0 staged (drains vmcnt)
    COMPUTE_Q(0, Bs);
    COMPUTE_Q(1, Bs + QB);
    __syncthreads();                    // readers done before overwrite

    stage_q(Wcb, 2, Bs, tid);
    stage_q(Wcb, 3, Bs + QB, tid);
    __syncthreads();                    // phase-1 staged
    COMPUTE_Q(2, Bs);
    COMPUTE_Q(3, Bs + QB);

    // ---- epilogue: sigmoid -> LDS rowbuf -> coalesced 448-B row stores
    const float* bg = megab + (size_t)g * DIM_OUT + (size_t)cb * BN;

    __syncthreads();                    // all waves done reading Bs (MFMA phase)

    float* rowbuf = (float*)Bs + wv * (16 * RBSTRIDE);   // per-wave 16-row slice
#pragma unroll
    for (int ns = 0; ns < NCB; ++ns) {
        int nloc = ns * 16 + r16;
        float bias = bg[nloc];
#pragma unroll
        for (int j = 0; j < 4; ++j) {
            float x = acc[ns][j] + bias;
            rowbuf[(kg * 4 + j) * RBSTRIDE + nloc] = 1.0f / (1.0f + __expf(-x));
        }
    }

    __syncthreads();                    // rowbuf complete (also wave-local order)

    const int* idxw = wsi + WS_IDX + startRow + wv * 16;
#pragma unroll
    for (int t = 0; t < 7; ++t) {
        int c = t * 64 + l;             // 0..447 = 16 rows x 28 chunks
        int row = c / 28;
        int cir = c - row * 28;         // 16-B chunk within row (0..27)
        if (wv * 16 + row < rc) {
            f32x4 v = *(const f32x4*)(rowbuf + row * RBSTRIDE + cir * 4);
            int orow = idxw[row];
            *(f32x4*)(out + (size_t)orow * DIM_OUT + cb * BN + cir * 4) = v;
        }
    }
}

// =============== fallback (round-4 path; needs only wbf) ===============
__launch_bounds__(256, 4)
__global__ void moe_gemm4_k(const float* __restrict__ theta,
                            const float* __restrict__ megab,
                            const int* __restrict__ wsi,
                            const short* __restrict__ wbf,
                            float* __restrict__ out) {
    __shared__ short Bsf[BN * 128];
    int Bid = blockIdx.x;
    const int q8 = G_BLOCKS / 8, r8 = G_BLOCKS % 8;
    int xcd = Bid & 7, slot = Bid >> 3;
    int w = (xcd < r8 ? xcd * (q8 + 1) : r8 * (q8 + 1) + (xcd - r8) * q8) + slot;
    int mt = w / NCB, cb = w % NCB;
    int total = wsi[24];
    if (mt >= total) return;
    int g = 0;
    while (mt >= wsi[12 + g + 1]) ++g;
    int lt    = mt - wsi[12 + g];
    int start = wsi[g];
    int cnt   = wsi[g + 1] - start;
    int row0  = lt * BM;
    int rc    = min(BM, cnt - row0);
    int tid = threadIdx.x;
    int wv = tid >> 6, l = tid & 63, r16 = l & 15, kg = l >> 4;
    const char* Wcb = (const char*)(wbf + ((size_t)g * DIM_OUT + (size_t)cb * BN) * DIM_IN);
#pragma unroll
    for (int it = 0; it < 7; ++it) {
        int lbyte = (it * 256 + tid) << 4;
        int L = lbyte ^ (((lbyte >> 8) & 7) << 4);
        int srcoff = ((L >> 8) << 9) + (L & 255);
        gload16(Wcb + srcoff, (char*)Bsf + lbyte);
    }
    const int* idxlist = wsi + WS_IDX + start + row0;
    int mloc = wv * 16 + r16;
    int asrc = (mloc < rc) ? idxlist[mloc] : idxlist[0];
    const float* Arow = theta + (size_t)asrc * DIM_IN;
    bf16x8 a[8];
#pragma unroll
    for (int ks = 0; ks < 8; ++ks) {
        int k0 = ks * 32 + kg * 8;
        f32x4 v0 = *(const f32x4*)(Arow + k0);
        f32x4 v1 = *(const f32x4*)(Arow + k0 + 4);
        bf16x8 af;
        af[0] = f2bf(v0[0]); af[1] = f2bf(v0[1]);
        af[2] = f2bf(v0[2]); af[3] = f2bf(v0[3]);
        af[4] = f2bf(v1[0]); af[5] = f2bf(v1[1]);
        af[6] = f2bf(v1[2]); af[7] = f2bf(v1[3]);
        a[ks] = af;
    }
    f32x4 acc[NCB];
#pragma unroll
    for (int ns = 0; ns < NCB; ++ns) acc[ns] = (f32x4){0.f, 0.f, 0.f, 0.f};
    __syncthreads();
#pragma unroll
    for (int ks = 0; ks < 4; ++ks)
#pragma unroll
        for (int ns = 0; ns < NCB; ++ns) {
            int n = ns * 16 + r16;
            int byte = (n << 8) + (ks << 6) + (kg << 4);
            byte ^= (n & 7) << 4;
            bf16x8 b = *(const bf16x8*)((const char*)Bsf + byte);
            acc[ns] = __builtin_amdgcn_mfma_f32_16x16x32_bf16(a[ks], b, acc[ns], 0, 0, 0);
        }
    __syncthreads();
#pragma unroll
    for (int it = 0; it < 7; ++it) {
        int lbyte = (it * 256 + tid) << 4;
        int L = lbyte ^ (((lbyte >> 8) & 7) << 4);
        int srcoff = ((L >> 8) << 9) + (L & 255) + 256;
        gload16(Wcb + srcoff, (char*)Bsf + lbyte);
    }
    __syncthreads();
#pragma unroll
    for (int ks = 0; ks < 4; ++ks)
#pragma unroll
        for (int ns = 0; ns < NCB; ++ns) {
            int n = ns * 16 + r16;
            int byte = (n << 8) + (ks << 6) + (kg << 4);
            byte ^= (n & 7) << 4;
            bf16x8 b = *(const bf16x8*)((const char*)Bsf + byte);
            acc[ns] = __builtin_amdgcn_mfma_f32_16x16x32_bf16(a[4 + ks], b, acc[ns], 0, 0, 0);
        }
    const float* bg = megab + (size_t)g * DIM_OUT + (size_t)cb * BN;
    int rbase = wv * 16 + kg * 4;
    int orow[4];
#pragma unroll
    for (int j = 0; j < 4; ++j)
        orow[j] = (rbase + j < rc) ? idxlist[rbase + j] : -1;
#pragma unroll
    for (int ns = 0; ns < NCB; ++ns) {
        int nloc = ns * 16 + r16;
        float bias = bg[nloc];
#pragma unroll
        for (int j = 0; j < 4; ++j) {
            if (orow[j] >= 0) {
                float x = acc[ns][j] + bias;
                out[(size_t)orow[j] * DIM_OUT + cb * BN + nloc] = 1.0f / (1.0f + __expf(-x));
            }
        }
    }
}

extern "C" void kernel_launch(void* const* d_in, const int* in_sizes, int n_in,
                              void* d_out, int out_size, void* d_ws, size_t ws_size,
                              hipStream_t stream) {
    const float* theta = (const float*)d_in[0];
    const int*   label = (const int*)d_in[1];
    const float* megaW = (const float*)d_in[2];
    const float* megab = (const float*)d_in[3];
    float* out = (float*)d_out;
    int* wsi = (int*)d_ws;
    short* wbf = (short*)((char*)d_ws + WS_WBF_BYTES);

    prep_k    <<<1012, 256, 0, stream>>>(megaW, label, wsi, wbf);
    scatter2_k<<<32, 512, 0, stream>>>(label, wsi);

    if (ws_size >= (size_t)WS_NEED) {
        short* thsort = (short*)((char*)d_ws + WS_TH_BYTES);
        gth_k      <<<2048, 256, 0, stream>>>(theta, wsi, thsort);
        moe_gemm11_k<<<G_BLOCKS, 256, 0, stream>>>(thsort, megab, wsi, wbf, out);
    } else {
        moe_gemm4_k<<<G_BLOCKS, 256, 0, stream>>>(theta, megab, wsi, wbf, out);
    }
}